// Round 2
// baseline (175.577 us; speedup 1.0000x reference)
//
#include <hip/hip_runtime.h>
#include <math.h>

#define NPT 512
#define BROWS 4096

typedef _Float16 half8 __attribute__((ext_vector_type(8)));
typedef float f32x4 __attribute__((ext_vector_type(4)));

__device__ __forceinline__ unsigned short f2h(float x) {
    _Float16 h = (_Float16)x;
    return __builtin_bit_cast(unsigned short, h);
}

__device__ __forceinline__ float sigmoidf_fast(float x) {
    return 1.0f / (1.0f + __expf(-x));
}

__global__ __launch_bounds__(512) void wps_kernel(
    const float* __restrict__ wp,    // (B, N, 2)
    const float* __restrict__ sww,   // scalar
    const float* __restrict__ W1,    // (4, 64)
    const float* __restrict__ b1,    // (64,)
    const float* __restrict__ W2,    // (64, 32)
    const float* __restrict__ b2,    // (32,)
    const float* __restrict__ W3,    // (32, 1)
    const float* __restrict__ b3,    // (1,)
    float* __restrict__ out)         // (B, N, 2)
{
    __shared__ float2 sPos[NPT];            // 4 KB
    __shared__ unsigned int sH1[256 * 32];  // 32 KB: 256 rows x 128B (64 f16 ch), XOR-swizzled
    __shared__ float sW[NPT];               // 2 KB

    const int t    = threadIdx.x;
    const int b    = blockIdx.x;
    const int lane = t & 63;
    const int wv   = t >> 6;

    const float2* wrow = (const float2*)(wp + (size_t)b * NPT * 2);
    sPos[t] = wrow[t];

    // ---- one-time: W2 B-fragments + per-lane constants ----
    // B[k][n] fragment (kstep ks, ntile nt): elem j <-> k = ks*32 + (lane>>4)*8 + j, n = nt*16 + (lane&15)
    half8 Bf00, Bf01, Bf10, Bf11;
    {
        const int kg = (lane >> 4) * 8;
        const int nn = lane & 15;
        half8 v0, v1, v2, v3;
        #pragma unroll
        for (int j = 0; j < 8; ++j) {
            v0[j] = (_Float16)W2[(0  + kg + j) * 32 + 0  + nn];
            v1[j] = (_Float16)W2[(0  + kg + j) * 32 + 16 + nn];
            v2[j] = (_Float16)W2[(32 + kg + j) * 32 + 0  + nn];
            v3[j] = (_Float16)W2[(32 + kg + j) * 32 + 16 + nn];
        }
        Bf00 = v0; Bf01 = v1; Bf10 = v2; Bf11 = v3;
    }
    const float b2a   = b2[lane & 15];
    const float b2b   = b2[16 + (lane & 15)];
    const float w3a   = W3[lane & 15];
    const float w3b   = W3[16 + (lane & 15)];
    const float bias3 = b3[0];
    const float swv   = sigmoidf_fast(sww[0]);

    __syncthreads();

    const int lr = t >> 1;   // local row 0..255 (point within half)
    const int cb = t & 1;    // channel block: ch [32*cb, 32*cb+32)

    #pragma unroll
    for (int h = 0; h < 2; ++h) {
        const int g = h * 256 + lr;   // global point index

        // ---- features (both threads of a pair compute redundantly) ----
        float2 p  = sPos[g];
        float2 pm = sPos[(g > 0) ? (g - 1) : 0];
        float2 pp = sPos[(g < NPT - 1) ? (g + 1) : (NPT - 1)];
        float d1x, d1y;
        if (g < NPT - 1) { d1x = pp.x - p.x; d1y = pp.y - p.y; }
        else             { d1x = p.x - pm.x; d1y = p.y - pm.y; }
        float d2x = 0.f, d2y = 0.f;
        if (g >= 1 && g <= NPT - 2) {
            d2x = pp.x - 2.f * p.x + pm.x;
            d2y = pp.y - 2.f * p.y + pm.y;
        }

        // ---- layer1 on VALU: 32 channels -> f16 -> swizzled LDS ----
        #pragma unroll
        for (int c8 = 0; c8 < 4; ++c8) {       // 4 chunks of 8 channels (16B)
            unsigned int wb[4];
            #pragma unroll
            for (int kp = 0; kp < 4; ++kp) {   // 2 channels per word
                const int ch = cb * 32 + c8 * 8 + kp * 2;
                float h0 = b1[ch];
                h0 = fmaf(d1x, W1[ch],       h0);
                h0 = fmaf(d1y, W1[64 + ch],  h0);
                h0 = fmaf(d2x, W1[128 + ch], h0);
                h0 = fmaf(d2y, W1[192 + ch], h0);
                float h1v = b1[ch + 1];
                h1v = fmaf(d1x, W1[ch + 1],       h1v);
                h1v = fmaf(d1y, W1[64 + ch + 1],  h1v);
                h1v = fmaf(d2x, W1[128 + ch + 1], h1v);
                h1v = fmaf(d2y, W1[192 + ch + 1], h1v);
                h0  = fmaxf(h0, 0.f);
                h1v = fmaxf(h1v, 0.f);
                wb[kp] = (unsigned int)f2h(h0) | ((unsigned int)f2h(h1v) << 16);
            }
            const int c    = cb * 4 + c8;                          // chunk 0..7
            const int widx = lr * 32 + ((c * 4) ^ ((lr & 7) << 2)); // word index, XOR swizzle
            *reinterpret_cast<uint4*>(&sH1[widx]) = make_uint4(wb[0], wb[1], wb[2], wb[3]);
        }

        __syncthreads();  // h1 tile complete

        // ---- layer2 MFMA + fused layer3 epilogue ----
        // wave wv owns local rows [wv*32, wv*32+32) -> two 16-row M-tiles
        #pragma unroll
        for (int s = 0; s < 2; ++s) {
            const int rb  = wv * 32 + s * 16;
            const int r   = rb + (lane & 15);
            const int cA0 = (lane >> 4);        // k 0..31
            const int cA1 = 4 + (lane >> 4);    // k 32..63
            const int wi0 = r * 32 + ((cA0 * 4) ^ ((r & 7) << 2));
            const int wi1 = r * 32 + ((cA1 * 4) ^ ((r & 7) << 2));
            half8 a0 = *reinterpret_cast<const half8*>(&sH1[wi0]);
            half8 a1 = *reinterpret_cast<const half8*>(&sH1[wi1]);

            f32x4 acc0 = {0.f, 0.f, 0.f, 0.f};
            f32x4 acc1 = {0.f, 0.f, 0.f, 0.f};
            acc0 = __builtin_amdgcn_mfma_f32_16x16x32_f16(a0, Bf00, acc0, 0, 0, 0);
            acc0 = __builtin_amdgcn_mfma_f32_16x16x32_f16(a1, Bf10, acc0, 0, 0, 0);
            acc1 = __builtin_amdgcn_mfma_f32_16x16x32_f16(a0, Bf01, acc1, 0, 0, 0);
            acc1 = __builtin_amdgcn_mfma_f32_16x16x32_f16(a1, Bf11, acc1, 0, 0, 0);

            // epilogue: v = sum_n relu(h2[n]) * W3[n]  (n spread over 16 lanes x 2 tiles)
            float wq[4];
            #pragma unroll
            for (int q = 0; q < 4; ++q) {
                float v = fmaxf(acc0[q] + b2a, 0.f) * w3a
                        + fmaxf(acc1[q] + b2b, 0.f) * w3b;
                v += __shfl_xor(v, 1);
                v += __shfl_xor(v, 2);
                v += __shfl_xor(v, 4);
                v += __shfl_xor(v, 8);
                float cw = sigmoidf_fast(v + bias3);
                wq[q] = swv * (1.f - cw);
            }
            if ((lane & 15) == 0) {
                const int r0 = h * 256 + rb + (lane >> 4) * 4;
                *reinterpret_cast<float4*>(&sW[r0]) = make_float4(wq[0], wq[1], wq[2], wq[3]);
            }
        }
        __syncthreads();  // sH1 safe to reuse / sW complete
    }

    // ---- linear recurrence: single-wave affine scan (lane owns 8 points) ----
    if (wv == 0) {
        const int base = lane * 8;
        float a8[8], cx8[8], cy8[8];
        float A = 1.f, Cx = 0.f, Cy = 0.f;
        #pragma unroll
        for (int i = 0; i < 8; ++i) {
            const int g = base + i;
            float2 p = sPos[g];
            float a, cx, cy;
            if (g == 0) { a = 0.f; cx = p.x; cy = p.y; }
            else { a = sW[g]; cx = (1.f - a) * p.x; cy = (1.f - a) * p.y; }
            a8[i] = a; cx8[i] = cx; cy8[i] = cy;
            Cx = fmaf(a, Cx, cx);
            Cy = fmaf(a, Cy, cy);
            A *= a;
        }
        #pragma unroll
        for (int d = 1; d < 64; d <<= 1) {
            float Ap  = __shfl_up(A, d);
            float Cpx = __shfl_up(Cx, d);
            float Cpy = __shfl_up(Cy, d);
            if (lane >= d) {
                Cx = fmaf(A, Cpx, Cx);
                Cy = fmaf(A, Cpy, Cy);
                A *= Ap;
            }
        }
        float yx = __shfl_up(Cx, 1);
        float yy = __shfl_up(Cy, 1);
        if (lane == 0) { yx = 0.f; yy = 0.f; }

        float4* orow = (float4*)(out + (size_t)b * NPT * 2);
        #pragma unroll
        for (int s2 = 0; s2 < 4; ++s2) {
            float x0, y0v, x1, y1v;
            { const int i = 2 * s2;
              yx = fmaf(a8[i], yx, cx8[i]); yy = fmaf(a8[i], yy, cy8[i]);
              x0 = yx; y0v = yy; }
            { const int i = 2 * s2 + 1;
              yx = fmaf(a8[i], yx, cx8[i]); yy = fmaf(a8[i], yy, cy8[i]);
              x1 = yx; y1v = yy; }
            if (lane == 63 && s2 == 3) {  // pin endpoint to original
                float2 pe = sPos[NPT - 1];
                x1 = pe.x; y1v = pe.y;
            }
            orow[lane * 4 + s2] = make_float4(x0, y0v, x1, y1v);
        }
    }
}

extern "C" void kernel_launch(void* const* d_in, const int* in_sizes, int n_in,
                              void* d_out, int out_size, void* d_ws, size_t ws_size,
                              hipStream_t stream) {
    const float* wp  = (const float*)d_in[0];
    const float* sww = (const float*)d_in[1];
    const float* W1  = (const float*)d_in[2];
    const float* b1  = (const float*)d_in[3];
    const float* W2  = (const float*)d_in[4];
    const float* b2  = (const float*)d_in[5];
    const float* W3  = (const float*)d_in[6];
    const float* b3  = (const float*)d_in[7];
    float* out = (float*)d_out;

    wps_kernel<<<BROWS, 512, 0, stream>>>(wp, sww, W1, b1, W2, b2, W3, b3, out);
}

// Round 3
// 47.687 us; speedup vs baseline: 3.6819x; 3.6819x over previous
//
#include <hip/hip_runtime.h>
#include <math.h>

#define NPT 512
#define BROWS 4096

typedef _Float16 half8 __attribute__((ext_vector_type(8)));
typedef _Float16 h2    __attribute__((ext_vector_type(2)));
typedef float    f32x4 __attribute__((ext_vector_type(4)));

__device__ __forceinline__ float sigmoidf_fast(float x) {
    return 1.0f / (1.0f + __expf(-x));
}

// one wave = one row; 4 waves/block; no __syncthreads anywhere
__global__ __launch_bounds__(256) void wps_kernel(
    const float* __restrict__ wp,    // (B, N, 2)
    const float* __restrict__ sww,
    const float* __restrict__ W1,    // (4, 64)
    const float* __restrict__ b1,    // (64,)
    const float* __restrict__ W2,    // (64, 32)
    const float* __restrict__ b2,    // (32,)
    const float* __restrict__ W3,    // (32, 1)
    const float* __restrict__ b3,    // (1,)
    float* __restrict__ out)
{
    __shared__ float sWv[4][NPT];    // raw pre-sigmoid logits, per-wave strip (8 KB)

    const int t    = threadIdx.x;
    const int lane = t & 63;
    const int wv   = t >> 6;
    const int row  = blockIdx.x * 4 + wv;

    const int nn = lane & 15;        // M-row within 16-pt chunk / N-col within tile
    const int kg = lane >> 4;        // k-group 0..3

    const float2* P = (const float2*)(wp + (size_t)row * NPT * 2);

    // ---- B fragments of W2 (layout verified in round 2) ----
    half8 Bf00, Bf01, Bf10, Bf11;
    {
        const int kg8 = kg * 8;
        #pragma unroll
        for (int j = 0; j < 8; ++j) {
            Bf00[j] = (_Float16)W2[(0  + kg8 + j) * 32 + 0  + nn];
            Bf01[j] = (_Float16)W2[(0  + kg8 + j) * 32 + 16 + nn];
            Bf10[j] = (_Float16)W2[(32 + kg8 + j) * 32 + 0  + nn];
            Bf11[j] = (_Float16)W2[(32 + kg8 + j) * 32 + 16 + nn];
        }
    }

    // ---- this lane's 16 layer-1 channels, f16-packed ----
    // low group: chans kg*8 + 2i, +1   (feeds k-step 0)
    // high group: chans 32 + kg*8 + 2i (feeds k-step 1)
    h2 w1pk[4][8];
    h2 b1pk[8];
    {
        const int cbase = kg * 8;
        #pragma unroll
        for (int i = 0; i < 8; ++i) {
            const int ch = (i < 4) ? (cbase + 2 * i) : (32 + cbase + 2 * (i - 4));
            #pragma unroll
            for (int k = 0; k < 4; ++k) {
                h2 v; v[0] = (_Float16)W1[k * 64 + ch]; v[1] = (_Float16)W1[k * 64 + ch + 1];
                w1pk[k][i] = v;
            }
            h2 bv; bv[0] = (_Float16)b1[ch]; bv[1] = (_Float16)b1[ch + 1];
            b1pk[i] = bv;
        }
    }

    const float b2a   = b2[nn];
    const float b2b   = b2[16 + nn];
    const float w3a   = W3[nn];
    const float w3b   = W3[16 + nn];
    const float bias3 = b3[0];
    const float swv   = sigmoidf_fast(sww[0]);

    // ---- MLP over 32 chunks of 16 points, software-pipelined loads ----
    float2 p_c, pm_c, pp_c;
    {
        const int g = nn;
        p_c  = P[g];
        pm_c = P[(g > 0) ? g - 1 : 0];
        pp_c = P[(g < NPT - 1) ? g + 1 : NPT - 1];
    }

    for (int c = 0; c < 32; ++c) {
        // prefetch next chunk's positions
        float2 p_n, pm_n, pp_n;
        {
            const int cn = (c < 31) ? c + 1 : c;
            const int g  = cn * 16 + nn;
            p_n  = P[g];
            pm_n = P[(g > 0) ? g - 1 : 0];
            pp_n = P[(g < NPT - 1) ? g + 1 : NPT - 1];
        }

        const int g = c * 16 + nn;
        float d1x, d1y;
        if (g < NPT - 1) { d1x = pp_c.x - p_c.x; d1y = pp_c.y - p_c.y; }
        else             { d1x = p_c.x - pm_c.x; d1y = p_c.y - pm_c.y; }
        float d2x = 0.f, d2y = 0.f;
        if (g >= 1 && g <= NPT - 2) {
            d2x = pp_c.x - 2.f * p_c.x + pm_c.x;
            d2y = pp_c.y - 2.f * p_c.y + pm_c.y;
        }

        h2 f0, f1, f2, f3;
        f0[0] = f0[1] = (_Float16)d1x;
        f1[0] = f1[1] = (_Float16)d1y;
        f2[0] = f2[1] = (_Float16)d2x;
        f3[0] = f3[1] = (_Float16)d2y;

        // layer 1: 8 channel-pairs, packed f16 FMA; outputs ARE the A-fragments
        union { half8 v; h2 p[4]; } A0, A1;
        #pragma unroll
        for (int i = 0; i < 8; ++i) {
            h2 h = b1pk[i];
            h += f0 * w1pk[0][i];
            h += f1 * w1pk[1][i];
            h += f2 * w1pk[2][i];
            h += f3 * w1pk[3][i];
            h2 z; z[0] = (_Float16)0.f; z[1] = (_Float16)0.f;
            h = __builtin_elementwise_max(h, z);
            if (i < 4) A0.p[i] = h; else A1.p[i - 4] = h;
        }

        // layer 2: verified 16x16x32 MFMA path
        f32x4 acc0 = {0.f, 0.f, 0.f, 0.f};
        f32x4 acc1 = {0.f, 0.f, 0.f, 0.f};
        acc0 = __builtin_amdgcn_mfma_f32_16x16x32_f16(A0.v, Bf00, acc0, 0, 0, 0);
        acc0 = __builtin_amdgcn_mfma_f32_16x16x32_f16(A1.v, Bf10, acc0, 0, 0, 0);
        acc1 = __builtin_amdgcn_mfma_f32_16x16x32_f16(A0.v, Bf01, acc1, 0, 0, 0);
        acc1 = __builtin_amdgcn_mfma_f32_16x16x32_f16(A1.v, Bf11, acc1, 0, 0, 0);

        // layer 3 partials + cross-col reduce (verified); store RAW logits
        float vq[4];
        #pragma unroll
        for (int q = 0; q < 4; ++q) {
            float v = fmaxf(acc0[q] + b2a, 0.f) * w3a
                    + fmaxf(acc1[q] + b2b, 0.f) * w3b;
            v += __shfl_xor(v, 1);
            v += __shfl_xor(v, 2);
            v += __shfl_xor(v, 4);
            v += __shfl_xor(v, 8);
            vq[q] = v;
        }
        if (nn == 0) {
            *reinterpret_cast<float4*>(&sWv[wv][c * 16 + kg * 4]) =
                make_float4(vq[0], vq[1], vq[2], vq[3]);
        }

        p_c = p_n; pm_c = pm_n; pp_c = pp_n;
    }

    // ---- scan: lane owns 8 consecutive points (verified round-2 pattern) ----
    {
        const int base = lane * 8;
        float wr[8];
        *reinterpret_cast<float4*>(&wr[0]) = *reinterpret_cast<const float4*>(&sWv[wv][base]);
        *reinterpret_cast<float4*>(&wr[4]) = *reinterpret_cast<const float4*>(&sWv[wv][base + 4]);

        const float4* P4 = (const float4*)P;
        float2 pts[8];
        #pragma unroll
        for (int s = 0; s < 4; ++s) {
            float4 v = P4[lane * 4 + s];
            pts[2 * s].x     = v.x; pts[2 * s].y     = v.y;
            pts[2 * s + 1].x = v.z; pts[2 * s + 1].y = v.w;
        }

        float a8[8], cx8[8], cy8[8];
        float A = 1.f, Cx = 0.f, Cy = 0.f;
        #pragma unroll
        for (int i = 0; i < 8; ++i) {
            const int g = base + i;
            float a = (g == 0) ? 0.f
                               : swv * (1.f - sigmoidf_fast(wr[i] + bias3));
            float cx = (1.f - a) * pts[i].x;
            float cy = (1.f - a) * pts[i].y;
            a8[i] = a; cx8[i] = cx; cy8[i] = cy;
            Cx = fmaf(a, Cx, cx);
            Cy = fmaf(a, Cy, cy);
            A *= a;
        }
        #pragma unroll
        for (int d = 1; d < 64; d <<= 1) {
            float Ap  = __shfl_up(A, d);
            float Cpx = __shfl_up(Cx, d);
            float Cpy = __shfl_up(Cy, d);
            if (lane >= d) {
                Cx = fmaf(A, Cpx, Cx);
                Cy = fmaf(A, Cpy, Cy);
                A *= Ap;
            }
        }
        float yx = __shfl_up(Cx, 1);
        float yy = __shfl_up(Cy, 1);
        if (lane == 0) { yx = 0.f; yy = 0.f; }

        float2 pe = P[NPT - 1];
        float4* orow = (float4*)(out + (size_t)row * NPT * 2);
        #pragma unroll
        for (int s2 = 0; s2 < 4; ++s2) {
            float x0, y0v, x1, y1v;
            { const int i = 2 * s2;
              yx = fmaf(a8[i], yx, cx8[i]); yy = fmaf(a8[i], yy, cy8[i]);
              x0 = yx; y0v = yy; }
            { const int i = 2 * s2 + 1;
              yx = fmaf(a8[i], yx, cx8[i]); yy = fmaf(a8[i], yy, cy8[i]);
              x1 = yx; y1v = yy; }
            if (lane == 63 && s2 == 3) { x1 = pe.x; y1v = pe.y; }
            orow[lane * 4 + s2] = make_float4(x0, y0v, x1, y1v);
        }
    }
}

extern "C" void kernel_launch(void* const* d_in, const int* in_sizes, int n_in,
                              void* d_out, int out_size, void* d_ws, size_t ws_size,
                              hipStream_t stream) {
    const float* wp  = (const float*)d_in[0];
    const float* sww = (const float*)d_in[1];
    const float* W1  = (const float*)d_in[2];
    const float* b1  = (const float*)d_in[3];
    const float* W2  = (const float*)d_in[4];
    const float* b2  = (const float*)d_in[5];
    const float* W3  = (const float*)d_in[6];
    const float* b3  = (const float*)d_in[7];
    float* out = (float*)d_out;

    wps_kernel<<<BROWS / 4, 256, 0, stream>>>(wp, sww, W1, b1, W2, b2, W3, b3, out);
}

// Round 4
// 38.993 us; speedup vs baseline: 4.5028x; 1.2230x over previous
//
#include <hip/hip_runtime.h>
#include <math.h>

#define NPT 512
#define BROWS 4096

typedef _Float16 half8 __attribute__((ext_vector_type(8)));
typedef _Float16 h2    __attribute__((ext_vector_type(2)));
typedef float    f32x4 __attribute__((ext_vector_type(4)));

__device__ __forceinline__ float sigmoidf_fast(float x) {
    return 1.0f / (1.0f + __expf(-x));
}

// block = 4 waves = 1 row. Wave wv computes chunks [wv*8, wv*8+8) of the MLP
// (chunks independent; features read global directly). One barrier, wave 0 scans.
__global__ __launch_bounds__(256) void wps_kernel(
    const float* __restrict__ wp,    // (B, N, 2)
    const float* __restrict__ sww,
    const float* __restrict__ W1,    // (4, 64)
    const float* __restrict__ b1,    // (64,)
    const float* __restrict__ W2,    // (64, 32)
    const float* __restrict__ b2,    // (32,)
    const float* __restrict__ W3,    // (32, 1)
    const float* __restrict__ b3,    // (1,)
    float* __restrict__ out)
{
    __shared__ float sLg[NPT];       // raw logits, 2 KB

    const int t    = threadIdx.x;
    const int lane = t & 63;
    const int wv   = t >> 6;
    const int row  = blockIdx.x;

    const int nn = lane & 15;        // point-in-chunk (B col / D col)
    const int kg = lane >> 4;        // k-group 0..3

    const float2* P = (const float2*)(wp + (size_t)row * NPT * 2);

    // ---- W2 fragments. Same contents as verified rounds 2/3; now used as the
    // A operand (W2^T): Af(tile t, kstep s)[j] = W2[(s*32+kg*8+j)*32 + t*16+nn]
    half8 Wf00, Wf01, Wf10, Wf11;
    {
        const int kg8 = kg * 8;
        #pragma unroll
        for (int j = 0; j < 8; ++j) {
            Wf00[j] = (_Float16)W2[(0  + kg8 + j) * 32 + 0  + nn];
            Wf01[j] = (_Float16)W2[(0  + kg8 + j) * 32 + 16 + nn];
            Wf10[j] = (_Float16)W2[(32 + kg8 + j) * 32 + 0  + nn];
            Wf11[j] = (_Float16)W2[(32 + kg8 + j) * 32 + 16 + nn];
        }
    }

    // ---- this lane's 16 layer-1 channels (= its B-fragment k-slice) ----
    h2 w1pk[4][8];
    h2 b1pk[8];
    {
        const int cbase = kg * 8;
        #pragma unroll
        for (int i = 0; i < 8; ++i) {
            const int ch = (i < 4) ? (cbase + 2 * i) : (32 + cbase + 2 * (i - 4));
            #pragma unroll
            for (int k = 0; k < 4; ++k) {
                h2 v; v[0] = (_Float16)W1[k * 64 + ch]; v[1] = (_Float16)W1[k * 64 + ch + 1];
                w1pk[k][i] = v;
            }
            h2 bv; bv[0] = (_Float16)b1[ch]; bv[1] = (_Float16)b1[ch + 1];
            b1pk[i] = bv;
        }
    }

    // per-lane epilogue constants: D row = kg*4+q (tile0), 16+kg*4+q (tile1)
    f32x4 accInit0, accInit1;
    float w3q0[4], w3q1[4];
    #pragma unroll
    for (int q = 0; q < 4; ++q) {
        const int ch = kg * 4 + q;
        accInit0[q] = b2[ch];
        accInit1[q] = b2[16 + ch];
        w3q0[q] = W3[ch];
        w3q1[q] = W3[16 + ch];
    }
    const float bias3 = b3[0];
    const float swv   = sigmoidf_fast(sww[0]);

    // ---- MLP over this wave's 8 chunks ----
    const int c0 = wv * 8;
    float2 p_c, pm_c, pp_c;
    {
        const int g = c0 * 16 + nn;
        p_c  = P[g];
        pm_c = P[(g > 0) ? g - 1 : 0];
        pp_c = P[(g < NPT - 1) ? g + 1 : NPT - 1];
    }

    #pragma unroll
    for (int cc = 0; cc < 8; ++cc) {
        const int c = c0 + cc;

        float2 p_n, pm_n, pp_n;
        {
            const int cn = (cc < 7) ? c + 1 : c;
            const int g  = cn * 16 + nn;
            p_n  = P[g];
            pm_n = P[(g > 0) ? g - 1 : 0];
            pp_n = P[(g < NPT - 1) ? g + 1 : NPT - 1];
        }

        const int g = c * 16 + nn;
        float d1x, d1y;
        if (g < NPT - 1) { d1x = pp_c.x - p_c.x; d1y = pp_c.y - p_c.y; }
        else             { d1x = p_c.x - pm_c.x; d1y = p_c.y - pm_c.y; }
        float d2x = 0.f, d2y = 0.f;
        if (g >= 1 && g <= NPT - 2) {
            d2x = pp_c.x - 2.f * p_c.x + pm_c.x;
            d2y = pp_c.y - 2.f * p_c.y + pm_c.y;
        }

        h2 f0, f1, f2, f3;
        f0[0] = f0[1] = (_Float16)d1x;
        f1[0] = f1[1] = (_Float16)d1y;
        f2[0] = f2[1] = (_Float16)d2x;
        f3[0] = f3[1] = (_Float16)d2y;

        // layer 1: outputs ARE this lane's B fragments (k-slice kg*8..+7, +32)
        union { half8 v; h2 p[4]; } H0, H1;
        #pragma unroll
        for (int i = 0; i < 8; ++i) {
            h2 h = b1pk[i];
            h += f0 * w1pk[0][i];
            h += f1 * w1pk[1][i];
            h += f2 * w1pk[2][i];
            h += f3 * w1pk[3][i];
            h2 z; z[0] = (_Float16)0.f; z[1] = (_Float16)0.f;
            h = __builtin_elementwise_max(h, z);
            if (i < 4) H0.p[i] = h; else H1.p[i - 4] = h;
        }

        // layer 2: A = W2^T fragments, B = h1 fragments; C init = b2 broadcast
        f32x4 acc0 = accInit0;
        f32x4 acc1 = accInit1;
        acc0 = __builtin_amdgcn_mfma_f32_16x16x32_f16(Wf00, H0.v, acc0, 0, 0, 0);
        acc0 = __builtin_amdgcn_mfma_f32_16x16x32_f16(Wf10, H1.v, acc0, 0, 0, 0);
        acc1 = __builtin_amdgcn_mfma_f32_16x16x32_f16(Wf01, H0.v, acc1, 0, 0, 0);
        acc1 = __builtin_amdgcn_mfma_f32_16x16x32_f16(Wf11, H1.v, acc1, 0, 0, 0);

        // layer 3: per-lane partial over 8 channels, then 2-step cross-lane sum
        float v = 0.f;
        #pragma unroll
        for (int q = 0; q < 4; ++q) {
            v = fmaf(fmaxf(acc0[q], 0.f), w3q0[q], v);
            v = fmaf(fmaxf(acc1[q], 0.f), w3q1[q], v);
        }
        v += __shfl_xor(v, 16);
        v += __shfl_xor(v, 32);
        if (lane < 16) sLg[c * 16 + nn] = v;

        p_c = p_n; pm_c = pm_n; pp_c = pp_n;
    }

    __syncthreads();

    // ---- scan: wave 0, lane owns 8 consecutive points (verified pattern) ----
    if (wv == 0) {
        const int base = lane * 8;
        float wr[8];
        *reinterpret_cast<float4*>(&wr[0]) = *reinterpret_cast<const float4*>(&sLg[base]);
        *reinterpret_cast<float4*>(&wr[4]) = *reinterpret_cast<const float4*>(&sLg[base + 4]);

        const float4* P4 = (const float4*)P;
        float2 pts[8];
        #pragma unroll
        for (int s = 0; s < 4; ++s) {
            float4 v = P4[lane * 4 + s];
            pts[2 * s].x     = v.x; pts[2 * s].y     = v.y;
            pts[2 * s + 1].x = v.z; pts[2 * s + 1].y = v.w;
        }

        float a8[8], cx8[8], cy8[8];
        float A = 1.f, Cx = 0.f, Cy = 0.f;
        #pragma unroll
        for (int i = 0; i < 8; ++i) {
            const int g = base + i;
            float a = (g == 0) ? 0.f
                               : swv * (1.f - sigmoidf_fast(wr[i] + bias3));
            float cx = (1.f - a) * pts[i].x;
            float cy = (1.f - a) * pts[i].y;
            a8[i] = a; cx8[i] = cx; cy8[i] = cy;
            Cx = fmaf(a, Cx, cx);
            Cy = fmaf(a, Cy, cy);
            A *= a;
        }
        #pragma unroll
        for (int d = 1; d < 64; d <<= 1) {
            float Ap  = __shfl_up(A, d);
            float Cpx = __shfl_up(Cx, d);
            float Cpy = __shfl_up(Cy, d);
            if (lane >= d) {
                Cx = fmaf(A, Cpx, Cx);
                Cy = fmaf(A, Cpy, Cy);
                A *= Ap;
            }
        }
        float yx = __shfl_up(Cx, 1);
        float yy = __shfl_up(Cy, 1);
        if (lane == 0) { yx = 0.f; yy = 0.f; }

        float2 pe = P[NPT - 1];
        float4* orow = (float4*)(out + (size_t)row * NPT * 2);
        #pragma unroll
        for (int s2 = 0; s2 < 4; ++s2) {
            float x0, y0v, x1, y1v;
            { const int i = 2 * s2;
              yx = fmaf(a8[i], yx, cx8[i]); yy = fmaf(a8[i], yy, cy8[i]);
              x0 = yx; y0v = yy; }
            { const int i = 2 * s2 + 1;
              yx = fmaf(a8[i], yx, cx8[i]); yy = fmaf(a8[i], yy, cy8[i]);
              x1 = yx; y1v = yy; }
            if (lane == 63 && s2 == 3) { x1 = pe.x; y1v = pe.y; }
            orow[lane * 4 + s2] = make_float4(x0, y0v, x1, y1v);
        }
    }
}

extern "C" void kernel_launch(void* const* d_in, const int* in_sizes, int n_in,
                              void* d_out, int out_size, void* d_ws, size_t ws_size,
                              hipStream_t stream) {
    const float* wp  = (const float*)d_in[0];
    const float* sww = (const float*)d_in[1];
    const float* W1  = (const float*)d_in[2];
    const float* b1  = (const float*)d_in[3];
    const float* W2  = (const float*)d_in[4];
    const float* b2  = (const float*)d_in[5];
    const float* W3  = (const float*)d_in[6];
    const float* b3  = (const float*)d_in[7];
    float* out = (float*)d_out;

    wps_kernel<<<BROWS, 256, 0, stream>>>(wp, sww, W1, b1, W2, b2, W3, b3, out);
}